// Round 5
// baseline (254.267 us; speedup 1.0000x reference)
//
#include <hip/hip_runtime.h>
#include <hip/hip_bf16.h>
#include <cstdint>

#define S_LEN 4096
#define D_DIM 512
#define NWIN  511
#define KDIM  8192
#define BMW   128                  // windows per tile
#define TROWS (8 * BMW + 8)        // 1032 x-rows per union A-tile
#define ASLOTS (TROWS * 8)         // 8256 16-byte slots

typedef __attribute__((ext_vector_type(8))) short short8;
typedef __attribute__((ext_vector_type(4))) float f32x4;

__device__ __forceinline__ unsigned short f2b(float f) {
    union { float f; unsigned int u; } v; v.f = f;
    unsigned int r = v.u + 0x7FFFu + ((v.u >> 16) & 1u);
    return (unsigned short)(r >> 16);
}

// ---------------------------------------------------------------------------
// Pre-pass: pack W [8192][512] fp32 into bf16 MFMA-fragment order.
// K-step s (t=s>>3, c0=s&7), wave-slot w, frag f=(n*2+k32), lane l, elem e:
//   value = W[t*512 + (s&7)*64 + k32*32 + (l>>4)*8 + e][64w + 16n + (l&15)]
//   at short8 slot ((s*8+w)*8 + f)*64 + l.   (verified R1-R4)
// ---------------------------------------------------------------------------
__global__ void wpack_kernel(const float* __restrict__ W, short8* __restrict__ pk) {
    __shared__ float tile[64][68];
    const int b2 = blockIdx.x;           // s*8 + w
    const int s = b2 >> 3, w = b2 & 7;
    const int t = s >> 3, c0 = (s & 7) << 6;
    const int tid = threadIdx.x;
    {
        int r = tid >> 2, c4 = (tid & 3) << 4;
        const float* src = W + (size_t)(t * 512 + c0 + r) * D_DIM + (w << 6) + c4;
#pragma unroll
        for (int j = 0; j < 4; ++j) {
            float4 v = *(const float4*)(src + 4 * j);
            tile[r][c4 + 4 * j + 0] = v.x;
            tile[r][c4 + 4 * j + 1] = v.y;
            tile[r][c4 + 4 * j + 2] = v.z;
            tile[r][c4 + 4 * j + 3] = v.w;
        }
    }
    __syncthreads();
    const int lane = tid & 63, f2 = tid >> 6;
#pragma unroll
    for (int ff = 0; ff < 2; ++ff) {
        int f = f2 * 2 + ff;
        int n = f >> 1, k32 = f & 1;
        short8 u;
#pragma unroll
        for (int e = 0; e < 8; ++e)
            u[e] = (short)f2b(tile[k32 * 32 + (lane >> 4) * 8 + e][n * 16 + (lane & 15)]);
        pk[((size_t)b2 * 8 + f) * 64 + lane] = u;
    }
}

__device__ __forceinline__ void load_b(const short8* __restrict__ pk, int s, int wslot,
                                       int lane, short8 (&b)[4][2]) {
    const short8* base = pk + ((size_t)(s * 8 + wslot) * 8) * 64 + lane;
#pragma unroll
    for (int n = 0; n < 4; ++n)
#pragma unroll
        for (int k32 = 0; k32 < 2; ++k32)
            b[n][k32] = base[(n * 2 + k32) * 64];
}

// ---- async A staging helpers (512-thread blocks, ASLOTS=8256 slots) -------
__device__ __forceinline__ void a_issue(const float* __restrict__ xb, int n0, int tid,
                                        int c0n, int i0, int cnt, float4 (&t)[3][2]) {
#pragma unroll
    for (int j = 0; j < 3; ++j) {
        if (j < cnt) {
            int slot = tid + (i0 + j) * 512;
            if (slot < ASLOTS) {
                int r = slot >> 3, k8 = slot & 7;
                int grow = 8 * n0 + r;
                if (grow > S_LEN - 1) grow = S_LEN - 1;
                const float* src = xb + (size_t)grow * D_DIM + (c0n << 6) + (k8 << 3);
                t[j][0] = *(const float4*)src;
                t[j][1] = *(const float4*)(src + 4);
            }
        }
    }
}

__device__ __forceinline__ void a_cvt(int tid, int i0, int cnt,
                                      const float4 (&t)[3][2], short8 (&su)[17]) {
#pragma unroll
    for (int j = 0; j < 3; ++j) {
        if (j < cnt) {
            int slot = tid + (i0 + j) * 512;
            if (slot < ASLOTS) {
                short8 u;
                u[0] = (short)f2b(t[j][0].x); u[1] = (short)f2b(t[j][0].y);
                u[2] = (short)f2b(t[j][0].z); u[3] = (short)f2b(t[j][0].w);
                u[4] = (short)f2b(t[j][1].x); u[5] = (short)f2b(t[j][1].y);
                u[6] = (short)f2b(t[j][1].z); u[7] = (short)f2b(t[j][1].w);
                su[i0 + j] = u;
            }
        }
    }
}

__device__ __forceinline__ void a_write(unsigned short* __restrict__ lsA, int tid,
                                        const short8 (&su)[17]) {
#pragma unroll
    for (int it = 0; it < 17; ++it) {
        int slot = tid + it * 512;
        if (slot < ASLOTS) {
            int r = slot >> 3, k8 = slot & 7;
            *(short8*)&lsA[(r << 6) + ((k8 ^ ((r >> 3) & 7)) << 3)] = su[it];
        }
    }
}

// ---------------------------------------------------------------------------
// Kernel A: windows-GEMM + bias + exact GELU -> hout (fp32, row-major).
// Block: (batch b, windows [n0,n0+128), col-half nc). 8 waves (2 row-halves x
// 4 col-slots), wave tile 64x64. 1 block/CU; A-tile 129 KB LDS single-buffer;
// A(c0+1) loads+converts overlap c0's t-steps; only ds_writes between barriers.
// nc fixed per XCD-half so each XCD L2 caches exactly its 4 MB pk half.
// ---------------------------------------------------------------------------
__global__ __launch_bounds__(512, 1)
void gemm_kernel(const float* __restrict__ x,
                 const short8* __restrict__ pk,
                 const float* __restrict__ bias,
                 float* __restrict__ hout)
{
    __shared__ __align__(16) unsigned short lsA[TROWS * 64];   // 129 KB

    const int p  = blockIdx.x;
    const int nc = (p & 7) >> 2;                 // XCD half -> B half
    const int g  = ((p >> 3) << 2) | (p & 3);    // 0..127
    const int b  = g >> 2;
    const int n0 = (g & 3) << 7;                 // window base (x128)
    const int tid  = threadIdx.x;
    const int lane = tid & 63, wid = tid >> 6;
    const int wr = wid >> 2, wc = wid & 3;
    const int wslot = nc * 4 + wc;               // global col-block 0..7
    const int r15 = lane & 15, hi = lane >> 4;
    const float* xb = x + (size_t)b * S_LEN * D_DIM;

    f32x4 acc[4][4] = {};
    short8 bc[4][2], bn[4][2];
    short8 su[17];
    float4 tmp0[3][2], tmp1[3][2];

    load_b(pk, 0, wslot, lane, bc);              // B(s=0) in flight over prologue

    // ---- prologue: stage A(c0=0) with light load/convert pipelining ----
    a_issue(xb, n0, tid, 0, 0, 3, tmp0);
#pragma unroll
    for (int k = 0; k < 6; ++k) {
        int cnt = (k < 5) ? 3 : 2;
        if (k < 5) {
            if (k & 1) a_issue(xb, n0, tid, 0, 3 * (k + 1), (k + 1 < 5) ? 3 : 2, tmp0);
            else       a_issue(xb, n0, tid, 0, 3 * (k + 1), (k + 1 < 5) ? 3 : 2, tmp1);
        }
        if (k & 1) a_cvt(tid, 3 * k, cnt, tmp1, su);
        else       a_cvt(tid, 3 * k, cnt, tmp0, su);
    }
    a_write(lsA, tid, su);
    asm volatile("s_waitcnt lgkmcnt(0)" ::: "memory");
    __builtin_amdgcn_s_barrier();
    __builtin_amdgcn_sched_barrier(0);

#define TSTEP(T, BCUR, BNXT)                                                   \
    {                                                                          \
        const int sn = ((T) < 15) ? (((T) + 1) * 8 + c0) : ((c0 + 1) & 7);     \
        load_b(pk, sn, wslot, lane, BNXT);                                     \
        short8 afr[4][2];                                                      \
        _Pragma("unroll")                                                      \
        for (int m = 0; m < 4; ++m) {                                          \
            int row = (((wr << 6) + (m << 4) + r15) << 3) + (T);               \
            int sb  = (r15 + ((T) >> 3)) & 7;                                  \
            _Pragma("unroll")                                                  \
            for (int k32 = 0; k32 < 2; ++k32) {                                \
                int swz = ((k32 << 2) + hi) ^ sb;                              \
                afr[m][k32] = *(const short8*)&lsA[(row << 6) + (swz << 3)];   \
            }                                                                  \
        }                                                                      \
        _Pragma("unroll")                                                      \
        for (int k32 = 0; k32 < 2; ++k32)                                      \
            _Pragma("unroll")                                                  \
            for (int m = 0; m < 4; ++m)                                        \
                _Pragma("unroll")                                              \
                for (int n = 0; n < 4; ++n)                                    \
                    acc[m][n] = __builtin_amdgcn_mfma_f32_16x16x32_bf16(       \
                        afr[m][k32], BCUR[n][k32], acc[m][n], 0, 0, 0);        \
    }

    for (int c0 = 0; c0 < 8; ++c0) {
        const int pf = (c0 < 7) ? 1 : 0;
        TSTEP(0, bc, bn)
        TSTEP(1, bn, bc)
        if (pf) a_issue(xb, n0, tid, c0 + 1, 0, 3, tmp0);
        TSTEP(2, bc, bn)
        TSTEP(3, bn, bc)
        if (pf) { a_cvt(tid, 0, 3, tmp0, su); a_issue(xb, n0, tid, c0 + 1, 3, 3, tmp1); }
        TSTEP(4, bc, bn)
        TSTEP(5, bn, bc)
        if (pf) { a_cvt(tid, 3, 3, tmp1, su); a_issue(xb, n0, tid, c0 + 1, 6, 3, tmp0); }
        TSTEP(6, bc, bn)
        TSTEP(7, bn, bc)
        if (pf) { a_cvt(tid, 6, 3, tmp0, su); a_issue(xb, n0, tid, c0 + 1, 9, 3, tmp1); }
        TSTEP(8, bc, bn)
        TSTEP(9, bn, bc)
        if (pf) { a_cvt(tid, 9, 3, tmp1, su); a_issue(xb, n0, tid, c0 + 1, 12, 3, tmp0); }
        TSTEP(10, bc, bn)
        TSTEP(11, bn, bc)
        if (pf) { a_cvt(tid, 12, 3, tmp0, su); a_issue(xb, n0, tid, c0 + 1, 15, 2, tmp1); }
        TSTEP(12, bc, bn)
        TSTEP(13, bn, bc)
        if (pf) a_cvt(tid, 15, 2, tmp1, su);
        TSTEP(14, bc, bn)
        TSTEP(15, bn, bc)
        __builtin_amdgcn_s_barrier();            // all waves done reading lsA
        if (pf) {
            a_write(lsA, tid, su);
            asm volatile("s_waitcnt lgkmcnt(0)" ::: "memory");
            __builtin_amdgcn_s_barrier();
            __builtin_amdgcn_sched_barrier(0);
        }
    }
#undef TSTEP

    // epilogue: bias + exact GELU -> hout[b][win][d]
    float bias4[4];
#pragma unroll
    for (int n = 0; n < 4; ++n)
        bias4[n] = bias[(wslot << 6) + (n << 4) + r15];
    float* hb = hout + (size_t)b * NWIN * D_DIM;
#pragma unroll
    for (int m = 0; m < 4; ++m) {
#pragma unroll
        for (int r = 0; r < 4; ++r) {
            int win = n0 + (wr << 6) + (m << 4) + (hi << 2) + r;
            if (win < NWIN) {
                size_t obase = (size_t)win * D_DIM + (wslot << 6) + r15;
#pragma unroll
                for (int n = 0; n < 4; ++n) {
                    float h = acc[m][n][r] + bias4[n];
                    float gl = 0.5f * h * (1.0f + erff(h * 0.70710678118654752f));
                    hb[obase + (n << 4)] = gl;
                }
            }
        }
    }
}

// ---------------------------------------------------------------------------
// Kernel B: row LayerNorm over D=512. One wave per row, grid-stride.
// ---------------------------------------------------------------------------
__global__ __launch_bounds__(256, 8)
void ln_kernel(const float* __restrict__ h, const float* __restrict__ gamma,
               const float* __restrict__ beta, float* __restrict__ out, int nrows)
{
    const int lane = threadIdx.x & 63;
    const int wv = blockIdx.x * 4 + (threadIdx.x >> 6);
    const int nw = gridDim.x * 4;
    float gm[8], bt[8];
#pragma unroll
    for (int j = 0; j < 8; ++j) {
        gm[j] = gamma[lane * 8 + j];
        bt[j] = beta[lane * 8 + j];
    }
    for (int row = wv; row < nrows; row += nw) {
        const float* src = h + (size_t)row * D_DIM + lane * 8;
        float4 v0 = *(const float4*)src;
        float4 v1 = *(const float4*)(src + 4);
        float s = v0.x + v0.y + v0.z + v0.w + v1.x + v1.y + v1.z + v1.w;
        float q = v0.x * v0.x + v0.y * v0.y + v0.z * v0.z + v0.w * v0.w +
                  v1.x * v1.x + v1.y * v1.y + v1.z * v1.z + v1.w * v1.w;
#pragma unroll
        for (int msk = 1; msk < 64; msk <<= 1) {
            s += __shfl_xor(s, msk, 64);
            q += __shfl_xor(q, msk, 64);
        }
        float mu  = s * (1.0f / 512.0f);
        float inv = rsqrtf(q * (1.0f / 512.0f) - mu * mu + 1e-5f);
        float o[8] = { v0.x, v0.y, v0.z, v0.w, v1.x, v1.y, v1.z, v1.w };
        float4 r0, r1;
        r0.x = (o[0] - mu) * inv * gm[0] + bt[0];
        r0.y = (o[1] - mu) * inv * gm[1] + bt[1];
        r0.z = (o[2] - mu) * inv * gm[2] + bt[2];
        r0.w = (o[3] - mu) * inv * gm[3] + bt[3];
        r1.x = (o[4] - mu) * inv * gm[4] + bt[4];
        r1.y = (o[5] - mu) * inv * gm[5] + bt[5];
        r1.z = (o[6] - mu) * inv * gm[6] + bt[6];
        r1.w = (o[7] - mu) * inv * gm[7] + bt[7];
        float* dst = out + (size_t)row * D_DIM + lane * 8;
        *(float4*)dst = r0;
        *(float4*)(dst + 4) = r1;
    }
}

// ---------------------------------------------------------------------------
// Fallback tier 1 (ws holds only pk): R3's verified fused kernel.
// ---------------------------------------------------------------------------
__global__ __launch_bounds__(512, 2)
void fused_kernel(const float* __restrict__ x,
                  const short8* __restrict__ pk,
                  const float* __restrict__ bias,
                  const float* __restrict__ gamma,
                  const float* __restrict__ beta,
                  float* __restrict__ out)
{
    __shared__ __align__(16) unsigned short lsAf[2][64 * 64];
    __shared__ float redS[8][64];
    __shared__ float redQ[8][64];

    const int blk = blockIdx.x;
    const int b  = blk >> 3;
    const int n0 = (blk & 7) << 6;
    const int tid = threadIdx.x;
    const int lane = tid & 63;
    const int wid  = tid >> 6;
    const int r15 = lane & 15, hi = lane >> 4;
    const int ai = tid >> 3, ak8 = tid & 7;
    const int akb = ak8 ^ (ai & 7);
    const float* xb = x + (size_t)b * S_LEN * D_DIM;

    f32x4 acc[4][4] = {};
    short8 bc[4][2], bn[4][2];
    {
        int row = 8 * (n0 + ai) + 0;
        if (row > S_LEN - 1) row = S_LEN - 1;
        const float* src = xb + (size_t)row * D_DIM + 0 + ak8 * 8;
        float4 f0 = *(const float4*)src;
        float4 f1 = *(const float4*)(src + 4);
        short8 u;
        u[0] = (short)f2b(f0.x); u[1] = (short)f2b(f0.y);
        u[2] = (short)f2b(f0.z); u[3] = (short)f2b(f0.w);
        u[4] = (short)f2b(f1.x); u[5] = (short)f2b(f1.y);
        u[6] = (short)f2b(f1.z); u[7] = (short)f2b(f1.w);
        *(short8*)&lsAf[0][ai * 64 + akb * 8] = u;
        load_b(pk, 0, wid, lane, bc);
    }
    __syncthreads();

#define STEP(S, CUR, NXT, BCUR, BNXT)                                          \
    {                                                                          \
        const int sn = ((S) + 1) & 127;                                        \
        const int tn = sn >> 3, c0n = (sn & 7) << 6;                           \
        int rown = 8 * (n0 + ai) + tn;                                         \
        if (rown > S_LEN - 1) rown = S_LEN - 1;                                \
        const float* asrc = xb + (size_t)rown * D_DIM + c0n + ak8 * 8;         \
        float4 f0 = *(const float4*)asrc;                                      \
        float4 f1 = *(const float4*)(asrc + 4);                                \
        load_b(pk, sn, wid, lane, BNXT);                                       \
        short8 afr[4][2];                                                      \
        _Pragma("unroll")                                                      \
        for (int m = 0; m < 4; ++m) {                                          \
            int row = 16 * m + r15;                                            \
            _Pragma("unroll")                                                  \
            for (int k32 = 0; k32 < 2; ++k32) {                                \
                int kb = (k32 * 4 + hi) ^ (row & 7);                           \
                afr[m][k32] = *(const short8*)&lsAf[CUR][row * 64 + kb * 8];   \
            }                                                                  \
        }                                                                      \
        _Pragma("unroll")                                                      \
        for (int k32 = 0; k32 < 2; ++k32)                                      \
            _Pragma("unroll")                                                  \
            for (int m = 0; m < 4; ++m)                                        \
                _Pragma("unroll")                                              \
                for (int n = 0; n < 4; ++n)                                    \
                    acc[m][n] = __builtin_amdgcn_mfma_f32_16x16x32_bf16(       \
                        afr[m][k32], BCUR[n][k32], acc[m][n], 0, 0, 0);        \
        short8 u;                                                              \
        u[0] = (short)f2b(f0.x); u[1] = (short)f2b(f0.y);                      \
        u[2] = (short)f2b(f0.z); u[3] = (short)f2b(f0.w);                      \
        u[4] = (short)f2b(f1.x); u[5] = (short)f2b(f1.y);                      \
        u[6] = (short)f2b(f1.z); u[7] = (short)f2b(f1.w);                      \
        *(short8*)&lsAf[NXT][ai * 64 + akb * 8] = u;                           \
        asm volatile("s_waitcnt lgkmcnt(0)" ::: "memory");                     \
        __builtin_amdgcn_s_barrier();                                          \
        __builtin_amdgcn_sched_barrier(0);                                     \
    }

    for (int it = 0; it < 64; ++it) {
        STEP(it * 2,     0, 1, bc, bn)
        STEP(it * 2 + 1, 1, 0, bn, bc)
    }
#undef STEP

    float bias4[4], gam4[4], bet4[4];
#pragma unroll
    for (int n = 0; n < 4; ++n) {
        int d = (wid << 6) + 16 * n + r15;
        bias4[n] = bias[d]; gam4[n] = gamma[d]; bet4[n] = beta[d];
    }
    float sum_[4][4], sq_[4][4];
#pragma unroll
    for (int m = 0; m < 4; ++m)
#pragma unroll
        for (int r = 0; r < 4; ++r) { sum_[m][r] = 0.f; sq_[m][r] = 0.f; }
#pragma unroll
    for (int m = 0; m < 4; ++m)
#pragma unroll
        for (int n = 0; n < 4; ++n)
#pragma unroll
            for (int r = 0; r < 4; ++r) {
                float h = acc[m][n][r] + bias4[n];
                float g = 0.5f * h * (1.0f + erff(h * 0.70710678118654752f));
                acc[m][n][r] = g;
                sum_[m][r] += g;
                sq_[m][r]  += g * g;
            }
#pragma unroll
    for (int m = 0; m < 4; ++m)
#pragma unroll
        for (int r = 0; r < 4; ++r) {
            float sv = sum_[m][r], qv = sq_[m][r];
#pragma unroll
            for (int msk = 1; msk < 16; msk <<= 1) {
                sv += __shfl_xor(sv, msk, 64);
                qv += __shfl_xor(qv, msk, 64);
            }
            sum_[m][r] = sv; sq_[m][r] = qv;
        }
    if (r15 == 0) {
#pragma unroll
        for (int m = 0; m < 4; ++m)
#pragma unroll
            for (int r = 0; r < 4; ++r) {
                int row16 = 16 * m + hi * 4 + r;
                redS[wid][row16] = sum_[m][r];
                redQ[wid][row16] = sq_[m][r];
            }
    }
    __syncthreads();
#pragma unroll
    for (int m = 0; m < 4; ++m) {
#pragma unroll
        for (int r = 0; r < 4; ++r) {
            int row16 = 16 * m + hi * 4 + r;
            float sv = 0.f, qv = 0.f;
#pragma unroll
            for (int w = 0; w < 8; ++w) { sv += redS[w][row16]; qv += redQ[w][row16]; }
            float mu  = sv * (1.0f / 512.0f);
            float var = qv * (1.0f / 512.0f) - mu * mu;
            float inv = rsqrtf(var + 1e-5f);
            int win = n0 + row16;
            if (win < NWIN) {
                size_t obase = ((size_t)b * NWIN + win) * D_DIM;
#pragma unroll
                for (int n = 0; n < 4; ++n) {
                    int d = (wid << 6) + 16 * n + r15;
                    out[obase + d] = (acc[m][n][r] - mu) * inv * gam4[n] + bet4[n];
                }
            }
        }
    }
}

// Fallback tier 2 (tiny ws): naive correct kernel.
__global__ void naive_kernel(const float* __restrict__ x, const float* __restrict__ W,
                             const float* __restrict__ bias, const float* __restrict__ gamma,
                             const float* __restrict__ beta, float* __restrict__ out) {
    __shared__ float hrow[D_DIM];
    __shared__ float red[2];
    const int b = blockIdx.x / NWIN, win = blockIdx.x % NWIN;
    const int d = threadIdx.x;
    float a = 0.f;
    for (int t = 0; t < 16; ++t) {
        const float* xr = x + ((size_t)b * S_LEN + 8 * win + t) * D_DIM;
        const float* wr = W + (size_t)t * D_DIM * D_DIM;
        for (int k = 0; k < D_DIM; ++k) a += xr[k] * wr[(size_t)k * D_DIM + d];
    }
    a += bias[d];
    a = 0.5f * a * (1.0f + erff(a * 0.70710678118654752f));
    hrow[d] = a;
    __syncthreads();
    if (d == 0) {
        float s = 0.f, q = 0.f;
        for (int k = 0; k < D_DIM; ++k) { s += hrow[k]; q += hrow[k] * hrow[k]; }
        float mu = s / D_DIM;
        red[0] = mu; red[1] = rsqrtf(q / D_DIM - mu * mu + 1e-5f);
    }
    __syncthreads();
    out[((size_t)b * NWIN + win) * D_DIM + d] = (a - red[0]) * red[1] * gamma[d] + beta[d];
}

extern "C" void kernel_launch(void* const* d_in, const int* in_sizes, int n_in,
                              void* d_out, int out_size, void* d_ws, size_t ws_size,
                              hipStream_t stream) {
    const float* x     = (const float*)d_in[0];
    const float* W     = (const float*)d_in[1];
    const float* bias  = (const float*)d_in[2];
    const float* gamma = (const float*)d_in[3];
    const float* beta  = (const float*)d_in[4];
    float* out = (float*)d_out;

    const size_t pk_bytes = (size_t)KDIM * D_DIM * sizeof(unsigned short);     // 8 MB
    const size_t h_bytes  = (size_t)32 * NWIN * D_DIM * sizeof(float);         // 33.5 MB

    if (ws_size >= pk_bytes + h_bytes) {
        short8* pk = (short8*)d_ws;
        float* hbuf = (float*)((char*)d_ws + pk_bytes);
        wpack_kernel<<<1024, 256, 0, stream>>>(W, pk);
        gemm_kernel<<<256, 512, 0, stream>>>(x, pk, bias, hbuf);
        ln_kernel<<<1024, 256, 0, stream>>>(hbuf, gamma, beta, out, 32 * NWIN);
    } else if (ws_size >= pk_bytes) {
        short8* pk = (short8*)d_ws;
        wpack_kernel<<<1024, 256, 0, stream>>>(W, pk);
        fused_kernel<<<256, 512, 0, stream>>>(x, pk, bias, gamma, beta, out);
    } else {
        naive_kernel<<<32 * NWIN, D_DIM, 0, stream>>>(x, W, bias, gamma, beta, out);
    }
}

// Round 6
// 176.468 us; speedup vs baseline: 1.4409x; 1.4409x over previous
//
#include <hip/hip_runtime.h>
#include <hip/hip_bf16.h>
#include <cstdint>

#define S_LEN 4096
#define D_DIM 512
#define NWIN  511
#define KDIM  8192
#define TROWS 520                 // 8*64+8 x-rows per union A-tile (BM=64)
#define ASLOTS (TROWS * 8)        // 4160 16-byte slots

typedef __attribute__((ext_vector_type(8))) short short8;
typedef __attribute__((ext_vector_type(4))) float f32x4;

__device__ __forceinline__ unsigned short f2b(float f) {
    union { float f; unsigned int u; } v; v.f = f;
    unsigned int r = v.u + 0x7FFFu + ((v.u >> 16) & 1u);
    return (unsigned short)(r >> 16);
}

// ---------------------------------------------------------------------------
// Pre-pass: pack W [8192][512] fp32 -> bf16 MFMA-fragment order, c0-major:
// K-step s (t=s>>3, c0=s&7) stored at q=(s&7)*16+(s>>3) so each c0's 16
// t-slices are one contiguous 1 MB stream (all blocks walk it in lockstep
// -> per-XCD L2 residency). Fragment mapping itself verified R1-R5:
//   value = W[t*512 + (s&7)*64 + k32*32 + (l>>4)*8 + e][64w + 16n + (l&15)]
//   at short8 slot ((q*8+w)*8 + (n*2+k32))*64 + l.
// ---------------------------------------------------------------------------
__global__ void wpack_kernel(const float* __restrict__ W, short8* __restrict__ pk) {
    __shared__ float tile[64][68];
    const int b2 = blockIdx.x;           // s*8 + w
    const int s = b2 >> 3, w = b2 & 7;
    const int t = s >> 3, c0 = s & 7;
    const int q = c0 * 16 + t;           // c0-major slot
    const int tid = threadIdx.x;
    {
        int r = tid >> 2, c4 = (tid & 3) << 4;
        const float* src = W + (size_t)(t * 512 + c0 * 64 + r) * D_DIM + (w << 6) + c4;
#pragma unroll
        for (int j = 0; j < 4; ++j) {
            float4 v = *(const float4*)(src + 4 * j);
            tile[r][c4 + 4 * j + 0] = v.x;
            tile[r][c4 + 4 * j + 1] = v.y;
            tile[r][c4 + 4 * j + 2] = v.z;
            tile[r][c4 + 4 * j + 3] = v.w;
        }
    }
    __syncthreads();
    const int lane = tid & 63, f2 = tid >> 6;
#pragma unroll
    for (int ff = 0; ff < 2; ++ff) {
        int f = f2 * 2 + ff;
        int n = f >> 1, k32 = f & 1;
        short8 u;
#pragma unroll
        for (int e = 0; e < 8; ++e)
            u[e] = (short)f2b(tile[k32 * 32 + (lane >> 4) * 8 + e][n * 16 + (lane & 15)]);
        pk[((size_t)q * 8 + w) * 8 * 64 + (size_t)f * 64 + lane] = u;
    }
}

__device__ __forceinline__ void load_b(const short8* __restrict__ pk, int q, int wslot,
                                       int lane, short8 (&bf)[4][2]) {
    const short8* base = pk + ((size_t)(q * 8 + wslot) * 8) * 64 + lane;
#pragma unroll
    for (int n = 0; n < 4; ++n)
#pragma unroll
        for (int k32 = 0; k32 < 2; ++k32)
            bf[n][k32] = base[(n * 2 + k32) * 64];
}

// ---------------------------------------------------------------------------
// Fused windows-GEMM + bias + exact GELU + in-block LayerNorm.
// Block: batch b, windows [n0,n0+64). 8 waves; wave w owns cols [64w,64w+64).
// A: union x-tile (520 rows x 64 k), fp32->bf16 reg-converted, DOUBLE-buffered
//    LDS (2x65KB) -> staged chunks written mid-c0, ONE barrier per c0.
// B: fragment-packed pk (c0-major) -> registers, 1-step prefetch.
// ---------------------------------------------------------------------------
__global__ __launch_bounds__(512, 2)
void fused_kernel(const float* __restrict__ x,
                  const short8* __restrict__ pk,
                  const float* __restrict__ bias,
                  const float* __restrict__ gamma,
                  const float* __restrict__ beta,
                  float* __restrict__ out)
{
    __shared__ __align__(16) unsigned short lsA[2][TROWS * 64];   // 2 x 65 KB
    __shared__ float redS[8][64];
    __shared__ float redQ[8][64];

    const int blk = blockIdx.x;
    const int b  = blk >> 3;
    const int n0 = (blk & 7) << 6;
    const int tid = threadIdx.x;
    const int lane = tid & 63;
    const int wid  = tid >> 6;
    const int r15 = lane & 15, hi = lane >> 4;
    const float* xb = x + (size_t)b * S_LEN * D_DIM;

    f32x4 acc[4][4] = {};
    short8 bc[4][2], bn[4][2];
    float4 ta[9][2];   // staging temps, literal-indexed only

#define CISSUE(J, C0N)                                                         \
    {                                                                          \
        if ((J) < 8 || tid < 64) {                                             \
            const int slot = tid + ((J) << 9);                                 \
            const int r = slot >> 3, k8 = slot & 7;                            \
            int grow = 8 * n0 + r;                                             \
            if (grow > S_LEN - 1) grow = S_LEN - 1;                            \
            const float* src = xb + (size_t)grow * D_DIM + ((C0N) << 6) + (k8 << 3); \
            ta[J][0] = *(const float4*)src;                                    \
            ta[J][1] = *(const float4*)(src + 4);                              \
        }                                                                      \
    }

#define CWRITE(J, DST)                                                         \
    {                                                                          \
        if ((J) < 8 || tid < 64) {                                             \
            const int slot = tid + ((J) << 9);                                 \
            const int r = slot >> 3, k8 = slot & 7;                            \
            short8 u;                                                          \
            u[0] = (short)f2b(ta[J][0].x); u[1] = (short)f2b(ta[J][0].y);      \
            u[2] = (short)f2b(ta[J][0].z); u[3] = (short)f2b(ta[J][0].w);      \
            u[4] = (short)f2b(ta[J][1].x); u[5] = (short)f2b(ta[J][1].y);      \
            u[6] = (short)f2b(ta[J][1].z); u[7] = (short)f2b(ta[J][1].w);      \
            *(short8*)&(DST)[(r << 6) + ((k8 ^ ((r >> 3) & 7)) << 3)] = u;     \
        }                                                                      \
    }

#define TSTEP(T, LA, BCUR, BNXT)                                               \
    {                                                                          \
        const int qn = (c0 * 16 + (T) + 1) & 127;                              \
        load_b(pk, qn, wid, lane, BNXT);                                       \
        short8 afr[4][2];                                                      \
        _Pragma("unroll")                                                      \
        for (int m = 0; m < 4; ++m) {                                          \
            const int row = (((m << 4) + r15) << 3) + (T);                     \
            const int sb  = (r15 + ((T) >> 3)) & 7;                            \
            _Pragma("unroll")                                                  \
            for (int k32 = 0; k32 < 2; ++k32)                                  \
                afr[m][k32] = *(const short8*)&(LA)[(row << 6) +               \
                                   ((((k32 << 2) + hi) ^ sb) << 3)];           \
        }                                                                      \
        _Pragma("unroll")                                                      \
        for (int k32 = 0; k32 < 2; ++k32)                                      \
            _Pragma("unroll")                                                  \
            for (int m = 0; m < 4; ++m)                                        \
                _Pragma("unroll")                                              \
                for (int n = 0; n < 4; ++n)                                    \
                    acc[m][n] = __builtin_amdgcn_mfma_f32_16x16x32_bf16(       \
                        afr[m][k32], BCUR[n][k32], acc[m][n], 0, 0, 0);        \
    }

    // ---- prologue: B(q=0) in flight, stage A(c0=0) into buf 0 ----
    load_b(pk, 0, wid, lane, bc);
    CISSUE(0, 0) CISSUE(1, 0) CISSUE(2, 0) CISSUE(3, 0) CISSUE(4, 0)
    CISSUE(5, 0) CISSUE(6, 0) CISSUE(7, 0) CISSUE(8, 0)
    CWRITE(0, lsA[0]) CWRITE(1, lsA[0]) CWRITE(2, lsA[0]) CWRITE(3, lsA[0])
    CWRITE(4, lsA[0]) CWRITE(5, lsA[0]) CWRITE(6, lsA[0]) CWRITE(7, lsA[0])
    CWRITE(8, lsA[0])
    asm volatile("s_waitcnt lgkmcnt(0)" ::: "memory");
    __builtin_amdgcn_s_barrier();
    __builtin_amdgcn_sched_barrier(0);

    // ---- main loop: 8 c0-slices, 16 barrier-free t-steps each ----
    for (int c0 = 0; c0 < 8; ++c0) {
        const unsigned short* La = lsA[c0 & 1];
        unsigned short* Ln = lsA[(c0 + 1) & 1];
        const int c0n = c0 + 1;
        const int pf = (c0 < 7);

        TSTEP(0, La, bc, bn)
        if (pf) { CISSUE(0, c0n) CISSUE(1, c0n) }
        TSTEP(1, La, bn, bc)
        TSTEP(2, La, bc, bn)
        if (pf) { CISSUE(2, c0n) CISSUE(3, c0n) }
        TSTEP(3, La, bn, bc)
        TSTEP(4, La, bc, bn)
        if (pf) { CISSUE(4, c0n) CISSUE(5, c0n) }
        TSTEP(5, La, bn, bc)
        TSTEP(6, La, bc, bn)
        if (pf) { CISSUE(6, c0n) CISSUE(7, c0n) }
        TSTEP(7, La, bn, bc)
        TSTEP(8, La, bc, bn)
        if (pf) { CISSUE(8, c0n) CWRITE(0, Ln) CWRITE(1, Ln) }
        TSTEP(9, La, bn, bc)
        TSTEP(10, La, bc, bn)
        if (pf) { CWRITE(2, Ln) CWRITE(3, Ln) }
        TSTEP(11, La, bn, bc)
        TSTEP(12, La, bc, bn)
        if (pf) { CWRITE(4, Ln) CWRITE(5, Ln) }
        TSTEP(13, La, bn, bc)
        TSTEP(14, La, bc, bn)
        if (pf) { CWRITE(6, Ln) CWRITE(7, Ln) CWRITE(8, Ln) }
        TSTEP(15, La, bn, bc)

        asm volatile("s_waitcnt lgkmcnt(0)" ::: "memory");
        __builtin_amdgcn_s_barrier();
        __builtin_amdgcn_sched_barrier(0);
    }
#undef TSTEP
#undef CISSUE
#undef CWRITE

    // ---- epilogue: bias + exact GELU + LayerNorm (verified R3) ----
    float bias4[4], gam4[4], bet4[4];
#pragma unroll
    for (int n = 0; n < 4; ++n) {
        int d = (wid << 6) + 16 * n + r15;
        bias4[n] = bias[d]; gam4[n] = gamma[d]; bet4[n] = beta[d];
    }
    float sum_[4][4], sq_[4][4];
#pragma unroll
    for (int m = 0; m < 4; ++m)
#pragma unroll
        for (int r = 0; r < 4; ++r) { sum_[m][r] = 0.f; sq_[m][r] = 0.f; }
#pragma unroll
    for (int m = 0; m < 4; ++m)
#pragma unroll
        for (int n = 0; n < 4; ++n)
#pragma unroll
            for (int r = 0; r < 4; ++r) {
                float h = acc[m][n][r] + bias4[n];
                float g = 0.5f * h * (1.0f + erff(h * 0.70710678118654752f));
                acc[m][n][r] = g;
                sum_[m][r] += g;
                sq_[m][r]  += g * g;
            }
#pragma unroll
    for (int m = 0; m < 4; ++m)
#pragma unroll
        for (int r = 0; r < 4; ++r) {
            float sv = sum_[m][r], qv = sq_[m][r];
#pragma unroll
            for (int msk = 1; msk < 16; msk <<= 1) {
                sv += __shfl_xor(sv, msk, 64);
                qv += __shfl_xor(qv, msk, 64);
            }
            sum_[m][r] = sv; sq_[m][r] = qv;
        }
    if (r15 == 0) {
#pragma unroll
        for (int m = 0; m < 4; ++m)
#pragma unroll
            for (int r = 0; r < 4; ++r) {
                int row16 = 16 * m + hi * 4 + r;
                redS[wid][row16] = sum_[m][r];
                redQ[wid][row16] = sq_[m][r];
            }
    }
    __syncthreads();
#pragma unroll
    for (int m = 0; m < 4; ++m) {
#pragma unroll
        for (int r = 0; r < 4; ++r) {
            int row16 = 16 * m + hi * 4 + r;
            float sv = 0.f, qv = 0.f;
#pragma unroll
            for (int w = 0; w < 8; ++w) { sv += redS[w][row16]; qv += redQ[w][row16]; }
            float mu  = sv * (1.0f / 512.0f);
            float var = qv * (1.0f / 512.0f) - mu * mu;
            float inv = rsqrtf(var + 1e-5f);
            int win = n0 + row16;
            if (win < NWIN) {
                size_t obase = ((size_t)b * NWIN + win) * D_DIM;
#pragma unroll
                for (int n = 0; n < 4; ++n) {
                    int d = (wid << 6) + 16 * n + r15;
                    out[obase + d] = (acc[m][n][r] - mu) * inv * gam4[n] + bet4[n];
                }
            }
        }
    }
}

// Fallback (tiny ws): naive correct kernel.
__global__ void naive_kernel(const float* __restrict__ x, const float* __restrict__ W,
                             const float* __restrict__ bias, const float* __restrict__ gamma,
                             const float* __restrict__ beta, float* __restrict__ out) {
    __shared__ float hrow[D_DIM];
    __shared__ float red[2];
    const int b = blockIdx.x / NWIN, win = blockIdx.x % NWIN;
    const int d = threadIdx.x;
    float a = 0.f;
    for (int t = 0; t < 16; ++t) {
        const float* xr = x + ((size_t)b * S_LEN + 8 * win + t) * D_DIM;
        const float* wr = W + (size_t)t * D_DIM * D_DIM;
        for (int k = 0; k < D_DIM; ++k) a += xr[k] * wr[(size_t)k * D_DIM + d];
    }
    a += bias[d];
    a = 0.5f * a * (1.0f + erff(a * 0.70710678118654752f));
    hrow[d] = a;
    __syncthreads();
    if (d == 0) {
        float s = 0.f, q = 0.f;
        for (int k = 0; k < D_DIM; ++k) { s += hrow[k]; q += hrow[k] * hrow[k]; }
        float mu = s / D_DIM;
        red[0] = mu; red[1] = rsqrtf(q / D_DIM - mu * mu + 1e-5f);
    }
    __syncthreads();
    out[((size_t)b * NWIN + win) * D_DIM + d] = (a - red[0]) * red[1] * gamma[d] + beta[d];
}

extern "C" void kernel_launch(void* const* d_in, const int* in_sizes, int n_in,
                              void* d_out, int out_size, void* d_ws, size_t ws_size,
                              hipStream_t stream) {
    const float* x     = (const float*)d_in[0];
    const float* W     = (const float*)d_in[1];
    const float* bias  = (const float*)d_in[2];
    const float* gamma = (const float*)d_in[3];
    const float* beta  = (const float*)d_in[4];
    float* out = (float*)d_out;

    const size_t pk_bytes = (size_t)KDIM * D_DIM * sizeof(unsigned short);  // 8 MB
    if (ws_size >= pk_bytes) {
        short8* pk = (short8*)d_ws;
        wpack_kernel<<<1024, 256, 0, stream>>>(W, pk);
        fused_kernel<<<256, 512, 0, stream>>>(x, pk, bias, gamma, beta, out);
    } else {
        naive_kernel<<<32 * NWIN, D_DIM, 0, stream>>>(x, W, bias, gamma, beta, out);
    }
}